// Round 2
// baseline (481.281 us; speedup 1.0000x reference)
//
#include <hip/hip_runtime.h>
#include <math.h>

#define S 8192
#define D 768
#define NA 256
#define NO 256
#define MAXW 40
#define NCAT 13
#define NPOL 3
#define NPROJ (2 + NCAT + NPOL)   // 18 projection columns: [valid0,valid1, cat0..12, pol0..2]

// out layout (flat fp32, reference return order)
#define OFF1 ((size_t)NA * NO * 2 * D)            // asp_ids
#define OFF2 (OFF1 + (size_t)NA * NO)             // opi_ids
#define OFF3 (OFF2 + (size_t)NA * NO)             // cate_out
#define OFF4 (OFF3 + (size_t)NA * NO * NCAT)      // polar_out
#define OFF5 (OFF4 + (size_t)NA * NO * NPOL)      // valid_mask

#define NEGF (-3.402823466e+38f)                  // jnp.finfo(f32).min

typedef float vfloat4 __attribute__((ext_vector_type(4)));

// ---------------------------------------------------------------------------
// Kernel 1: per-span max-pool + projection partials. One block per span.
// (unchanged from R1 — isolates the store-path change in kernel 2)
// ---------------------------------------------------------------------------
__global__ __launch_bounds__(256) void span_pool_proj(
    const float* __restrict__ word_rep,
    const int*   __restrict__ aspects,
    const int*   __restrict__ opinions,
    const float* __restrict__ W_valid,   // (1536,2) row-major
    const float* __restrict__ W_cat,     // (1536,13)
    const float* __restrict__ W_pol,     // (1536,3)
    float*  __restrict__ rep_out,
    double* __restrict__ proj_out)
{
    __shared__ float  rep[D];
    __shared__ double part[4][NPROJ];
    const int b = blockIdx.x;     // 0..511
    const int t = threadIdx.x;    // 0..255

    const int* spans = (b < NA) ? aspects : opinions;
    const int  s     = (b < NA) ? b : (b - NA);
    const int  woff  = (b < NA) ? 0 : D;

    const int head  = spans[2 * s];
    const int tail  = spans[2 * s + 1];
    const int width = tail - head;         // 1..40

    if (t < 192) {
        const vfloat4* base = (const vfloat4*)(word_rep + (size_t)head * D) + t;
        vfloat4 m = base[0];
#pragma unroll
        for (int r = 1; r < MAXW; ++r) {
            vfloat4 v = base[(size_t)r * (D / 4)];
            const bool ok = r < width;
            m.x = fmaxf(m.x, ok ? v.x : NEGF);
            m.y = fmaxf(m.y, ok ? v.y : NEGF);
            m.z = fmaxf(m.z, ok ? v.z : NEGF);
            m.w = fmaxf(m.w, ok ? v.w : NEGF);
        }
        ((vfloat4*)rep)[t] = m;
        ((vfloat4*)(rep_out + (size_t)b * D))[t] = m;
    }
    __syncthreads();

    const int w    = t >> 6;   // wave 0..3 -> d-chunk [w*192, w*192+192)
    const int lane = t & 63;
    if (lane < NPROJ) {
        const float* W; int ncol, col;
        if (lane < 2)           { W = W_valid; ncol = 2;    col = lane; }
        else if (lane < 2+NCAT) { W = W_cat;   ncol = NCAT; col = lane - 2; }
        else                    { W = W_pol;   ncol = NPOL; col = lane - 2 - NCAT; }
        const int d0 = w * (D / 4);          // 192-wide chunk
        double a0 = 0.0, a1 = 0.0;           // 2 accumulators break the dep chain
#pragma unroll 8
        for (int d = d0; d < d0 + (D / 4); d += 2) {
            a0 += (double)rep[d]     * (double)W[(size_t)(woff + d)     * ncol + col];
            a1 += (double)rep[d + 1] * (double)W[(size_t)(woff + d + 1) * ncol + col];
        }
        part[w][lane] = a0 + a1;
    }
    __syncthreads();
    if (t < NPROJ)
        proj_out[(size_t)b * NPROJ + t] =
            (part[0][t] + part[1][t]) + (part[2][t] + part[3][t]);
}

// ---------------------------------------------------------------------------
// Kernel 2: fused pair outputs. 1024 blocks x 384 threads; block = (aspect i,
// 64-pair j-chunk).
// R2 changes: (a) PLAIN stores for the 402.6 MB out0 stream — R0/R1 both used
// nontemporal stores and both capped at ~2.3 TB/s effective, while the
// harness's plain-store fill hits 6.25 TB/s on the same buffer; (b) all 64
// masks precomputed per-wave via __ballot (bit-identical f64 expression), so
// the store loop has no per-iteration scalar-load latency chain; (c) opinion
// rep loaded unconditionally + cndmask-selected -> software-pipelineable.
// ---------------------------------------------------------------------------
#define JPB 64

__global__ __launch_bounds__(384) void pair_out(
    const vfloat4* __restrict__ rep4,     // 512 rows x 192 float4
    const double*  __restrict__ proj,     // 512 x 18
    const float*   __restrict__ b_valid,
    const float*   __restrict__ b_cat,
    const float*   __restrict__ b_pol,
    float*         __restrict__ out)
{
    const int blk = blockIdx.x;           // 0..1023
    const int i   = blk >> 2;             // aspect 0..255
    const int j0  = (blk & 3) * JPB;      // 0,64,128,192
    const int t   = threadIdx.x;          // 0..383
    const int l   = t & 63;               // lane in wave

    const double pa0 = proj[(size_t)i * NPROJ + 0];
    const double pa1 = proj[(size_t)i * NPROJ + 1];
    const double bv0 = (double)b_valid[0];
    const double bv1 = (double)b_valid[1];

    // Per-wave ballot of the 64 masks for this j-chunk. Lane l evaluates
    // j = j0 + l with the exact same f64 expression/order as before ->
    // bit-identical mask bits. All 6 waves compute the same 64-bit word.
    const double q0 = proj[(size_t)(NA + j0 + l) * NPROJ + 0];
    const double q1 = proj[(size_t)(NA + j0 + l) * NPROJ + 1];
    const unsigned long long mb = __ballot((pa0 + q0 + bv0) > (pa1 + q1 + bv1));

    vfloat4 av = (vfloat4)0.f;
    if (t < 192) av = rep4[(size_t)i * 192 + t];

    // small-output role for lanes 192..210: c = 0..12 cate, 13..15 pol,
    // 16 asp_id, 17 opi_id, 18 valid_mask
    const int c = t - 192;
    double pac = 0.0; float bias = 0.0f;
    if (c >= 0 && c < 16) {
        pac  = proj[(size_t)i * NPROJ + 2 + c];
        bias = (c < NCAT) ? b_cat[c] : b_pol[c - NCAT];
    }

    const double* po  = proj + (size_t)(NA + j0) * NPROJ;   // uniform -> s_loads
    vfloat4*      dst = (vfloat4*)out + (size_t)((i << 8) | j0) * 384 + t;

#pragma unroll 4
    for (int jj = 0; jj < JPB; ++jj) {
        const int j = j0 + jj;
        const int p = (i << 8) | j;
        const bool mask = (mb >> jj) & 1ULL;

        // Unconditional load (waves 3..5 only; L2-resident), select by mask.
        vfloat4 src = (t < 192) ? av
                                : rep4[(size_t)(NA + j) * 192 + (t - 192)];
        vfloat4 val = mask ? src : (vfloat4)0.f;
        dst[0] = val;                       // plain streaming store (not NT)

        if (c >= 0 && c < 16) {
            float v = mask ? (float)(pac + po[2 + c] + (double)bias) : 0.0f;
            if (c < NCAT) out[OFF3 + (size_t)p * NCAT + c] = v;
            else          out[OFF4 + (size_t)p * NPOL + (c - NCAT)] = v;
        } else if (c == 16) {
            out[OFF1 + p] = mask ? (float)i : -1.0f;
        } else if (c == 17) {
            out[OFF2 + p] = mask ? (float)j : -1.0f;
        } else if (c == 18) {
            out[OFF5 + p] = mask ? 1.0f : 0.0f;
        }

        po  += NPROJ;
        dst += 384;
    }
}

extern "C" void kernel_launch(void* const* d_in, const int* in_sizes, int n_in,
                              void* d_out, int out_size, void* d_ws, size_t ws_size,
                              hipStream_t stream)
{
    const float* word_rep = (const float*)d_in[0];   // (8192,768)
    const int*   aspects  = (const int*)  d_in[1];   // (256,2)
    const int*   opinions = (const int*)  d_in[2];   // (256,2)
    const float* W_valid  = (const float*)d_in[3];   // (1536,2)
    const float* b_valid  = (const float*)d_in[4];   // (2,)
    const float* W_cat    = (const float*)d_in[5];   // (1536,13)
    const float* b_cat    = (const float*)d_in[6];   // (13,)
    const float* W_pol    = (const float*)d_in[7];   // (1536,3)
    const float* b_pol    = (const float*)d_in[8];   // (3,)
    float* out = (float*)d_out;

    // ws layout: rep (512*768 f32 = 1.5 MB) | proj (512*18 f64)
    float*  rep  = (float*)d_ws;
    double* proj = (double*)((char*)d_ws + (size_t)(NA + NO) * D * sizeof(float));

    span_pool_proj<<<NA + NO, 256, 0, stream>>>(
        word_rep, aspects, opinions, W_valid, W_cat, W_pol, rep, proj);

    pair_out<<<NA * 4, 384, 0, stream>>>(
        (const vfloat4*)rep, proj, b_valid, b_cat, b_pol, out);
}

// Round 3
// 446.094 us; speedup vs baseline: 1.0789x; 1.0789x over previous
//
#include <hip/hip_runtime.h>
#include <math.h>

#define S 8192
#define D 768
#define NA 256
#define NO 256
#define MAXW 40
#define NCAT 13
#define NPOL 3
#define NPROJ (2 + NCAT + NPOL)   // 18 projection columns: [valid0,valid1, cat0..12, pol0..2]

// out layout (flat fp32, reference return order)
#define OFF1 ((size_t)NA * NO * 2 * D)            // asp_ids
#define OFF2 (OFF1 + (size_t)NA * NO)             // opi_ids
#define OFF3 (OFF2 + (size_t)NA * NO)             // cate_out
#define OFF4 (OFF3 + (size_t)NA * NO * NCAT)      // polar_out
#define OFF5 (OFF4 + (size_t)NA * NO * NPOL)      // valid_mask

#define NEGF (-3.402823466e+38f)                  // jnp.finfo(f32).min

typedef float vfloat4 __attribute__((ext_vector_type(4)));

// ---------------------------------------------------------------------------
// Kernel 1: per-span max-pool + projection partials. One block per span.
// R3: pool loop chunked into 8-row granules with wave-uniform early exit
// (width is block-uniform) -> avg 24 rows loaded instead of unconditional 40,
// while keeping full MLP within each granule. All loads provably in-bounds
// (head <= S-MAXW-1).
// ---------------------------------------------------------------------------
__global__ __launch_bounds__(256) void span_pool_proj(
    const float* __restrict__ word_rep,
    const int*   __restrict__ aspects,
    const int*   __restrict__ opinions,
    const float* __restrict__ W_valid,   // (1536,2) row-major
    const float* __restrict__ W_cat,     // (1536,13)
    const float* __restrict__ W_pol,     // (1536,3)
    float*  __restrict__ rep_out,
    double* __restrict__ proj_out)
{
    __shared__ float  rep[D];
    __shared__ double part[4][NPROJ];
    const int b = blockIdx.x;     // 0..511
    const int t = threadIdx.x;    // 0..255

    const int* spans = (b < NA) ? aspects : opinions;
    const int  s     = (b < NA) ? b : (b - NA);
    const int  woff  = (b < NA) ? 0 : D;

    const int head  = spans[2 * s];
    const int tail  = spans[2 * s + 1];
    const int width = tail - head;         // 1..40 (block-uniform)

    if (t < 192) {
        const vfloat4* base = (const vfloat4*)(word_rep + (size_t)head * D) + t;
        vfloat4 m = base[0];
#pragma unroll
        for (int g = 0; g < MAXW; g += 8) {        // 8-row granules
            if (g && g >= width) break;            // uniform branch (width uniform)
            const int rbeg = g ? g : 1;
#pragma unroll
            for (int r = rbeg; r < g + 8; ++r) {
                vfloat4 v = base[(size_t)r * (D / 4)];
                const bool ok = r < width;
                m.x = fmaxf(m.x, ok ? v.x : NEGF);
                m.y = fmaxf(m.y, ok ? v.y : NEGF);
                m.z = fmaxf(m.z, ok ? v.z : NEGF);
                m.w = fmaxf(m.w, ok ? v.w : NEGF);
            }
        }
        ((vfloat4*)rep)[t] = m;
        ((vfloat4*)(rep_out + (size_t)b * D))[t] = m;
    }
    __syncthreads();

    const int w    = t >> 6;   // wave 0..3 -> d-chunk [w*192, w*192+192)
    const int lane = t & 63;
    if (lane < NPROJ) {
        const float* W; int ncol, col;
        if (lane < 2)           { W = W_valid; ncol = 2;    col = lane; }
        else if (lane < 2+NCAT) { W = W_cat;   ncol = NCAT; col = lane - 2; }
        else                    { W = W_pol;   ncol = NPOL; col = lane - 2 - NCAT; }
        const int d0 = w * (D / 4);          // 192-wide chunk
        double a0 = 0.0, a1 = 0.0;           // 2 accumulators break the dep chain
#pragma unroll 8
        for (int d = d0; d < d0 + (D / 4); d += 2) {
            a0 += (double)rep[d]     * (double)W[(size_t)(woff + d)     * ncol + col];
            a1 += (double)rep[d + 1] * (double)W[(size_t)(woff + d + 1) * ncol + col];
        }
        part[w][lane] = a0 + a1;
    }
    __syncthreads();
    if (t < NPROJ)
        proj_out[(size_t)b * NPROJ + t] =
            (part[0][t] + part[1][t]) + (part[2][t] + part[3][t]);
}

// ---------------------------------------------------------------------------
// Kernel 2: fused pair outputs. 1024 blocks x 384 threads; block = (aspect i,
// 64-pair j-chunk).
// R3 changes: (a) small outputs (ids/mask/cate/pol) hoisted OUT of the hot
// loop into a fully-coalesced float4 epilogue -> the 64-deep loop is a pure
// {load-select-store} stream with no scattered 4B stores and no branch code;
// (b) per-wave-role split loops: waves 0-2 store the register-resident aspect
// vec (zero loads), waves 3-5 stream opinion vecs from L2; (c) unroll 8.
// Mask bits via __ballot with the exact R1/R2 f64 expression -> bit-identical.
// ---------------------------------------------------------------------------
#define JPB 64

__global__ __launch_bounds__(384) void pair_out(
    const vfloat4* __restrict__ rep4,     // 512 rows x 192 float4
    const double*  __restrict__ proj,     // 512 x 18
    const float*   __restrict__ b_valid,
    const float*   __restrict__ b_cat,
    const float*   __restrict__ b_pol,
    float*         __restrict__ out)
{
    const int blk = blockIdx.x;           // 0..1023
    const int i   = blk >> 2;             // aspect 0..255
    const int j0  = (blk & 3) * JPB;      // 0,64,128,192
    const int t   = threadIdx.x;          // 0..383
    const int l   = t & 63;               // lane in wave

    const double pa0 = proj[(size_t)i * NPROJ + 0];
    const double pa1 = proj[(size_t)i * NPROJ + 1];
    const double bv0 = (double)b_valid[0];
    const double bv1 = (double)b_valid[1];

    // Per-wave ballot of the 64 masks for this j-chunk (lane l <-> j0+l).
    // Same f64 expression/order as pair_small originally -> bit-identical.
    const double q0 = proj[(size_t)(NA + j0 + l) * NPROJ + 0];
    const double q1 = proj[(size_t)(NA + j0 + l) * NPROJ + 1];
    const unsigned long long mb = __ballot((pa0 + q0 + bv0) > (pa1 + q1 + bv1));

    vfloat4* dst = (vfloat4*)out + (size_t)((i << 8) | j0) * 384 + t;

    if (t < 192) {
        // waves 0-2: aspect half, register-resident, no loads in the loop
        const vfloat4 av = rep4[(size_t)i * 192 + t];
#pragma unroll 8
        for (int jj = 0; jj < JPB; ++jj) {
            vfloat4 val = ((mb >> jj) & 1ULL) ? av : (vfloat4)0.f;
            dst[0] = val;
            dst += 384;
        }
    } else {
        // waves 3-5: opinion half, streamed from L2
        const vfloat4* osrc = rep4 + (size_t)(NA + j0) * 192 + (t - 192);
#pragma unroll 8
        for (int jj = 0; jj < JPB; ++jj) {
            vfloat4 v   = osrc[0];
            vfloat4 val = ((mb >> jj) & 1ULL) ? v : (vfloat4)0.f;
            dst[0] = val;
            osrc += 192;
            dst  += 384;
        }
    }

    // ------------------ coalesced small-output epilogue -------------------
    // cate: 64*13 = 832 f32 = 208 float4 | pol: 64*3 = 192 f32 = 48 float4
    // asp_ids/opi_ids/mask: 64 f32 = 16 float4 each. All bases 16B-aligned
    // (p0 % 4 == 0). Values use the same f64 expression as before.
    const int p0 = (i << 8) | j0;

    if (t < 208) {                                   // cate_out
        const int e0 = t * 4;
        vfloat4 v;
#pragma unroll
        for (int k = 0; k < 4; ++k) {
            const int e  = e0 + k;
            const int jj = e / NCAT;
            const int c  = e % NCAT;
            const bool mk = (mb >> jj) & 1ULL;
            const double pac = proj[(size_t)i * NPROJ + 2 + c];
            const double poc = proj[(size_t)(NA + j0 + jj) * NPROJ + 2 + c];
            v[k] = mk ? (float)(pac + poc + (double)b_cat[c]) : 0.0f;
        }
        *(vfloat4*)(out + OFF3 + (size_t)p0 * NCAT + e0) = v;
    } else if (t < 256) {                            // polar_out
        const int e0 = (t - 208) * 4;
        vfloat4 v;
#pragma unroll
        for (int k = 0; k < 4; ++k) {
            const int e  = e0 + k;
            const int jj = e / NPOL;
            const int c  = e % NPOL;
            const bool mk = (mb >> jj) & 1ULL;
            const double pac = proj[(size_t)i * NPROJ + 2 + NCAT + c];
            const double poc = proj[(size_t)(NA + j0 + jj) * NPROJ + 2 + NCAT + c];
            v[k] = mk ? (float)(pac + poc + (double)b_pol[c]) : 0.0f;
        }
        *(vfloat4*)(out + OFF4 + (size_t)p0 * NPOL + e0) = v;
    } else if (t < 272) {                            // asp_ids
        const int e0 = (t - 256) * 4;
        vfloat4 v;
#pragma unroll
        for (int k = 0; k < 4; ++k)
            v[k] = ((mb >> (e0 + k)) & 1ULL) ? (float)i : -1.0f;
        *(vfloat4*)(out + OFF1 + (size_t)p0 + e0) = v;
    } else if (t < 288) {                            // opi_ids
        const int e0 = (t - 272) * 4;
        vfloat4 v;
#pragma unroll
        for (int k = 0; k < 4; ++k)
            v[k] = ((mb >> (e0 + k)) & 1ULL) ? (float)(j0 + e0 + k) : -1.0f;
        *(vfloat4*)(out + OFF2 + (size_t)p0 + e0) = v;
    } else if (t < 304) {                            // valid_mask
        const int e0 = (t - 288) * 4;
        vfloat4 v;
#pragma unroll
        for (int k = 0; k < 4; ++k)
            v[k] = ((mb >> (e0 + k)) & 1ULL) ? 1.0f : 0.0f;
        *(vfloat4*)(out + OFF5 + (size_t)p0 + e0) = v;
    }
}

extern "C" void kernel_launch(void* const* d_in, const int* in_sizes, int n_in,
                              void* d_out, int out_size, void* d_ws, size_t ws_size,
                              hipStream_t stream)
{
    const float* word_rep = (const float*)d_in[0];   // (8192,768)
    const int*   aspects  = (const int*)  d_in[1];   // (256,2)
    const int*   opinions = (const int*)  d_in[2];   // (256,2)
    const float* W_valid  = (const float*)d_in[3];   // (1536,2)
    const float* b_valid  = (const float*)d_in[4];   // (2,)
    const float* W_cat    = (const float*)d_in[5];   // (1536,13)
    const float* b_cat    = (const float*)d_in[6];   // (13,)
    const float* W_pol    = (const float*)d_in[7];   // (1536,3)
    const float* b_pol    = (const float*)d_in[8];   // (3,)
    float* out = (float*)d_out;

    // ws layout: rep (512*768 f32 = 1.5 MB) | proj (512*18 f64)
    float*  rep  = (float*)d_ws;
    double* proj = (double*)((char*)d_ws + (size_t)(NA + NO) * D * sizeof(float));

    span_pool_proj<<<NA + NO, 256, 0, stream>>>(
        word_rep, aspects, opinions, W_valid, W_cat, W_pol, rep, proj);

    pair_out<<<NA * 4, 384, 0, stream>>>(
        (const vfloat4*)rep, proj, b_valid, b_cat, b_pol, out);
}

// Round 4
// 441.649 us; speedup vs baseline: 1.0897x; 1.0101x over previous
//
#include <hip/hip_runtime.h>
#include <math.h>

#define S 8192
#define D 768
#define NA 256
#define NO 256
#define MAXW 40
#define NCAT 13
#define NPOL 3
#define NPROJ (2 + NCAT + NPOL)   // 18 projection columns: [valid0,valid1, cat0..12, pol0..2]

// out layout (flat fp32, reference return order)
#define OFF1 ((size_t)NA * NO * 2 * D)            // asp_ids
#define OFF2 (OFF1 + (size_t)NA * NO)             // opi_ids
#define OFF3 (OFF2 + (size_t)NA * NO)             // cate_out
#define OFF4 (OFF3 + (size_t)NA * NO * NCAT)      // polar_out
#define OFF5 (OFF4 + (size_t)NA * NO * NPOL)      // valid_mask

#define NEGF (-3.402823466e+38f)                  // jnp.finfo(f32).min

typedef float vfloat4 __attribute__((ext_vector_type(4)));

// ---------------------------------------------------------------------------
// Kernel 1: per-span max-pool + projection partials. One block per span.
// R4: 384 threads. Pooling split by row PARITY across two 192-lane groups
// (waves 0-2: even rows, waves 3-5: odd rows; <=20 rows each, granule-5
// uniform early exit), LDS fmax combine -> half the per-lane pool work.
// f64 projection split 6-way (128-wide d-chunks) -> shorter dep chains.
// All loads provably in-bounds (head <= S-MAXW-1).
// ---------------------------------------------------------------------------
__global__ __launch_bounds__(384) void span_pool_proj(
    const float* __restrict__ word_rep,
    const int*   __restrict__ aspects,
    const int*   __restrict__ opinions,
    const float* __restrict__ W_valid,   // (1536,2) row-major
    const float* __restrict__ W_cat,     // (1536,13)
    const float* __restrict__ W_pol,     // (1536,3)
    float*  __restrict__ rep_out,
    double* __restrict__ proj_out)
{
    __shared__ float   rep[D];
    __shared__ vfloat4 part0[192];           // even-row partial maxes
    __shared__ double  partp[6][NPROJ];
    const int b = blockIdx.x;     // 0..511
    const int t = threadIdx.x;    // 0..383

    const int* spans = (b < NA) ? aspects : opinions;
    const int  s     = (b < NA) ? b : (b - NA);
    const int  woff  = (b < NA) ? 0 : D;

    const int head  = spans[2 * s];
    const int tail  = spans[2 * s + 1];
    const int width = tail - head;           // 1..40 (block-uniform)

    const int g = (t >= 192) ? 1 : 0;        // row parity (wave-uniform)
    const int c = g ? (t - 192) : t;         // column 0..191

    {
        const vfloat4* base = (const vfloat4*)(word_rep + (size_t)head * D) + c;
        vfloat4 m = (vfloat4)NEGF;
#pragma unroll
        for (int k = 0; k < MAXW / 2; ++k) {         // rows r = 2k + g
            if (k == 5 || k == 10 || k == 15) {      // granule early exit
                if (2 * k + g >= width) break;       // uniform per wave
            }
            const int r = 2 * k + g;
            vfloat4 v = base[(size_t)r * (D / 4)];
            const bool ok = r < width;
            m.x = fmaxf(m.x, ok ? v.x : NEGF);
            m.y = fmaxf(m.y, ok ? v.y : NEGF);
            m.z = fmaxf(m.z, ok ? v.z : NEGF);
            m.w = fmaxf(m.w, ok ? v.w : NEGF);
        }
        if (!g) part0[c] = m;
        __syncthreads();
        if (g) {
            vfloat4 p = part0[c];
            m.x = fmaxf(m.x, p.x);
            m.y = fmaxf(m.y, p.y);
            m.z = fmaxf(m.z, p.z);
            m.w = fmaxf(m.w, p.w);
            ((vfloat4*)rep)[c] = m;
            ((vfloat4*)(rep_out + (size_t)b * D))[c] = m;
        }
    }
    __syncthreads();

    const int w    = t >> 6;   // wave 0..5 -> d-chunk [w*128, w*128+128)
    const int lane = t & 63;
    if (lane < NPROJ) {
        const float* W; int ncol, col;
        if (lane < 2)           { W = W_valid; ncol = 2;    col = lane; }
        else if (lane < 2+NCAT) { W = W_cat;   ncol = NCAT; col = lane - 2; }
        else                    { W = W_pol;   ncol = NPOL; col = lane - 2 - NCAT; }
        const int d0 = w * (D / 6);          // 128-wide chunk
        double a0 = 0.0, a1 = 0.0;           // 2 accumulators break the dep chain
#pragma unroll 8
        for (int d = d0; d < d0 + (D / 6); d += 2) {
            a0 += (double)rep[d]     * (double)W[(size_t)(woff + d)     * ncol + col];
            a1 += (double)rep[d + 1] * (double)W[(size_t)(woff + d + 1) * ncol + col];
        }
        partp[w][lane] = a0 + a1;
    }
    __syncthreads();
    if (t < NPROJ)
        proj_out[(size_t)b * NPROJ + t] =
            ((partp[0][t] + partp[1][t]) + (partp[2][t] + partp[3][t]))
          +  (partp[4][t] + partp[5][t]);
}

// ---------------------------------------------------------------------------
// Kernel 2: fused pair outputs (R3 structure). 1024 blocks x 384 threads;
// block = (aspect i, 64-pair j-chunk).
// R4 change: NONTEMPORAL stores for the 402.6 MB out0 stream on the clean
// (hoisted-epilogue) structure. A/B history: NT was never tested here —
// R1(NT, pre-hoist)=463 vs R2(plain, pre-hoist)=481 says NT is worth ~15 µs
// (evict-first avoids double-handling 402 MB of dirty lines in L2).
// Epilogue small outputs stay plain.
// ---------------------------------------------------------------------------
#define JPB 64

__global__ __launch_bounds__(384) void pair_out(
    const vfloat4* __restrict__ rep4,     // 512 rows x 192 float4
    const double*  __restrict__ proj,     // 512 x 18
    const float*   __restrict__ b_valid,
    const float*   __restrict__ b_cat,
    const float*   __restrict__ b_pol,
    float*         __restrict__ out)
{
    const int blk = blockIdx.x;           // 0..1023
    const int i   = blk >> 2;             // aspect 0..255
    const int j0  = (blk & 3) * JPB;      // 0,64,128,192
    const int t   = threadIdx.x;          // 0..383
    const int l   = t & 63;               // lane in wave

    const double pa0 = proj[(size_t)i * NPROJ + 0];
    const double pa1 = proj[(size_t)i * NPROJ + 1];
    const double bv0 = (double)b_valid[0];
    const double bv1 = (double)b_valid[1];

    // Per-wave ballot of the 64 masks for this j-chunk (lane l <-> j0+l).
    // Same f64 expression/order as the original pair_small -> bit-identical.
    const double q0 = proj[(size_t)(NA + j0 + l) * NPROJ + 0];
    const double q1 = proj[(size_t)(NA + j0 + l) * NPROJ + 1];
    const unsigned long long mb = __ballot((pa0 + q0 + bv0) > (pa1 + q1 + bv1));

    vfloat4* dst = (vfloat4*)out + (size_t)((i << 8) | j0) * 384 + t;

    if (t < 192) {
        // waves 0-2: aspect half, register-resident, no loads in the loop
        const vfloat4 av = rep4[(size_t)i * 192 + t];
#pragma unroll 8
        for (int jj = 0; jj < JPB; ++jj) {
            vfloat4 val = ((mb >> jj) & 1ULL) ? av : (vfloat4)0.f;
            __builtin_nontemporal_store(val, dst);
            dst += 384;
        }
    } else {
        // waves 3-5: opinion half, streamed from L2
        const vfloat4* osrc = rep4 + (size_t)(NA + j0) * 192 + (t - 192);
#pragma unroll 8
        for (int jj = 0; jj < JPB; ++jj) {
            vfloat4 v   = osrc[0];
            vfloat4 val = ((mb >> jj) & 1ULL) ? v : (vfloat4)0.f;
            __builtin_nontemporal_store(val, dst);
            osrc += 192;
            dst  += 384;
        }
    }

    // ------------------ coalesced small-output epilogue -------------------
    // cate: 64*13 = 832 f32 = 208 float4 | pol: 64*3 = 192 f32 = 48 float4
    // asp_ids/opi_ids/mask: 64 f32 = 16 float4 each. All bases 16B-aligned
    // (p0 % 4 == 0). Values use the same f64 expression as before.
    const int p0 = (i << 8) | j0;

    if (t < 208) {                                   // cate_out
        const int e0 = t * 4;
        vfloat4 v;
#pragma unroll
        for (int k = 0; k < 4; ++k) {
            const int e  = e0 + k;
            const int jj = e / NCAT;
            const int c  = e % NCAT;
            const bool mk = (mb >> jj) & 1ULL;
            const double pac = proj[(size_t)i * NPROJ + 2 + c];
            const double poc = proj[(size_t)(NA + j0 + jj) * NPROJ + 2 + c];
            v[k] = mk ? (float)(pac + poc + (double)b_cat[c]) : 0.0f;
        }
        *(vfloat4*)(out + OFF3 + (size_t)p0 * NCAT + e0) = v;
    } else if (t < 256) {                            // polar_out
        const int e0 = (t - 208) * 4;
        vfloat4 v;
#pragma unroll
        for (int k = 0; k < 4; ++k) {
            const int e  = e0 + k;
            const int jj = e / NPOL;
            const int c  = e % NPOL;
            const bool mk = (mb >> jj) & 1ULL;
            const double pac = proj[(size_t)i * NPROJ + 2 + NCAT + c];
            const double poc = proj[(size_t)(NA + j0 + jj) * NPROJ + 2 + NCAT + c];
            v[k] = mk ? (float)(pac + poc + (double)b_pol[c]) : 0.0f;
        }
        *(vfloat4*)(out + OFF4 + (size_t)p0 * NPOL + e0) = v;
    } else if (t < 272) {                            // asp_ids
        const int e0 = (t - 256) * 4;
        vfloat4 v;
#pragma unroll
        for (int k = 0; k < 4; ++k)
            v[k] = ((mb >> (e0 + k)) & 1ULL) ? (float)i : -1.0f;
        *(vfloat4*)(out + OFF1 + (size_t)p0 + e0) = v;
    } else if (t < 288) {                            // opi_ids
        const int e0 = (t - 272) * 4;
        vfloat4 v;
#pragma unroll
        for (int k = 0; k < 4; ++k)
            v[k] = ((mb >> (e0 + k)) & 1ULL) ? (float)(j0 + e0 + k) : -1.0f;
        *(vfloat4*)(out + OFF2 + (size_t)p0 + e0) = v;
    } else if (t < 304) {                            // valid_mask
        const int e0 = (t - 288) * 4;
        vfloat4 v;
#pragma unroll
        for (int k = 0; k < 4; ++k)
            v[k] = ((mb >> (e0 + k)) & 1ULL) ? 1.0f : 0.0f;
        *(vfloat4*)(out + OFF5 + (size_t)p0 + e0) = v;
    }
}

extern "C" void kernel_launch(void* const* d_in, const int* in_sizes, int n_in,
                              void* d_out, int out_size, void* d_ws, size_t ws_size,
                              hipStream_t stream)
{
    const float* word_rep = (const float*)d_in[0];   // (8192,768)
    const int*   aspects  = (const int*)  d_in[1];   // (256,2)
    const int*   opinions = (const int*)  d_in[2];   // (256,2)
    const float* W_valid  = (const float*)d_in[3];   // (1536,2)
    const float* b_valid  = (const float*)d_in[4];   // (2,)
    const float* W_cat    = (const float*)d_in[5];   // (1536,13)
    const float* b_cat    = (const float*)d_in[6];   // (13,)
    const float* W_pol    = (const float*)d_in[7];   // (1536,3)
    const float* b_pol    = (const float*)d_in[8];   // (3,)
    float* out = (float*)d_out;

    // ws layout: rep (512*768 f32 = 1.5 MB) | proj (512*18 f64)
    float*  rep  = (float*)d_ws;
    double* proj = (double*)((char*)d_ws + (size_t)(NA + NO) * D * sizeof(float));

    span_pool_proj<<<NA + NO, 384, 0, stream>>>(
        word_rep, aspects, opinions, W_valid, W_cat, W_pol, rep, proj);

    pair_out<<<NA * 4, 384, 0, stream>>>(
        (const vfloat4*)rep, proj, b_valid, b_cat, b_pol, out);
}